// Round 1
// baseline (139.621 us; speedup 1.0000x reference)
//
#include <hip/hip_runtime.h>
#include <hip/hip_bf16.h>
#include <math.h>

// PINN forward + Taylor-mode derivatives, closed form.
// Outputs per point: [u, u_x, u_xx, w, w_x, w_xx, w_xxx, w_xxxx]  (row-major [N,8])

__device__ __forceinline__ float tanh_fast(float z) {
    // tanh(z) = 1 - 2/(exp(2z)+1); clamp so exp never overflows (tanh saturates anyway)
    z = fminf(15.f, fmaxf(-15.f, z));
    // exp(2z) = exp2(2z * log2(e))
    float e = __expf(2.f * z);
    return (e - 1.f) / (e + 1.f);
}

__global__ __launch_bounds__(256) void pinn_taylor_kernel(
    const float* __restrict__ x,
    const float* __restrict__ W0, const float* __restrict__ b0,
    const float* __restrict__ W1, const float* __restrict__ b1,
    const float* __restrict__ W2, const float* __restrict__ b2,
    float* __restrict__ out, int n)
{
    int i = blockIdx.x * blockDim.x + threadIdx.x;
    if (i >= n) return;

    const float xv = x[i];  // L0 == 1.0

    // ---------------- layer 0: z = a*x + b (affine in x) ----------------
    // h0 derivatives 0..4 for each of 8 neurons
    float h0[5][8];
    #pragma unroll
    for (int j = 0; j < 8; ++j) {
        const float a = W0[j];           // W0 shape (8,1)
        const float z = fmaf(a, xv, b0[j]);
        const float t = tanh_fast(z);
        const float s = fmaf(-t, t, 1.f);         // 1 - t^2
        const float T1 = s;
        const float T2 = -2.f * t * s;
        const float T3 = fmaf(4.f * t * t, s, -2.f * s * s);   // -2s^2 + 4 t^2 s
        const float T4 = t * s * fmaf(-8.f, t * t, 16.f * s);  // 16 t s^2 - 8 t^3 s
        const float a2 = a * a;
        h0[0][j] = t;
        h0[1][j] = a * T1;
        h0[2][j] = a2 * T2;
        h0[3][j] = a2 * a * T3;
        h0[4][j] = a2 * a2 * T4;
    }

    // ---------------- layer 1: matvec over 5 Taylor orders + tanh (Faa di Bruno) ----
    float h1[5][8];
    #pragma unroll
    for (int ii = 0; ii < 8; ++ii) {
        float g0 = b1[ii], g1 = 0.f, g2 = 0.f, g3 = 0.f, g4 = 0.f;
        #pragma unroll
        for (int j = 0; j < 8; ++j) {
            const float w = W1[ii * 8 + j];   // W1 shape (8,8) row-major
            g0 = fmaf(w, h0[0][j], g0);
            g1 = fmaf(w, h0[1][j], g1);
            g2 = fmaf(w, h0[2][j], g2);
            g3 = fmaf(w, h0[3][j], g3);
            g4 = fmaf(w, h0[4][j], g4);
        }
        const float t = tanh_fast(g0);
        const float s = fmaf(-t, t, 1.f);
        const float T1 = s;
        const float T2 = -2.f * t * s;
        const float T3 = fmaf(4.f * t * t, s, -2.f * s * s);
        const float T4 = t * s * fmaf(-8.f, t * t, 16.f * s);

        const float g1_2 = g1 * g1;
        h1[0][ii] = t;
        h1[1][ii] = T1 * g1;
        h1[2][ii] = fmaf(T2, g1_2, T1 * g2);
        h1[3][ii] = fmaf(T3, g1_2 * g1, fmaf(3.f * T2, g1 * g2, T1 * g3));
        h1[4][ii] = fmaf(T4, g1_2 * g1_2,
                     fmaf(6.f * T3, g1_2 * g2,
                      fmaf(T2, fmaf(3.f, g2 * g2, 4.f * g1 * g3), T1 * g4)));
    }

    // ---------------- layer 2: linear ----------------
    float o[2][5];
    #pragma unroll
    for (int k = 0; k < 2; ++k) {
        float o0 = b2[k], o1 = 0.f, o2 = 0.f, o3 = 0.f, o4 = 0.f;
        #pragma unroll
        for (int j = 0; j < 8; ++j) {
            const float w = W2[k * 8 + j];   // W2 shape (2,8) row-major
            o0 = fmaf(w, h1[0][j], o0);
            o1 = fmaf(w, h1[1][j], o1);
            o2 = fmaf(w, h1[2][j], o2);
            o3 = fmaf(w, h1[3][j], o3);
            o4 = fmaf(w, h1[4][j], o4);
        }
        o[k][0] = o0; o[k][1] = o1; o[k][2] = o2; o[k][3] = o3; o[k][4] = o4;
    }

    // output row: u, u_x, u_xx, w, w_x, w_xx, w_xxx, w_xxxx
    float4* out4 = reinterpret_cast<float4*>(out);
    out4[2 * i + 0] = make_float4(o[0][0], o[0][1], o[0][2], o[1][0]);
    out4[2 * i + 1] = make_float4(o[1][1], o[1][2], o[1][3], o[1][4]);
}

extern "C" void kernel_launch(void* const* d_in, const int* in_sizes, int n_in,
                              void* d_out, int out_size, void* d_ws, size_t ws_size,
                              hipStream_t stream) {
    const float* x  = (const float*)d_in[0];
    const float* W0 = (const float*)d_in[1];
    const float* b0 = (const float*)d_in[2];
    const float* W1 = (const float*)d_in[3];
    const float* b1 = (const float*)d_in[4];
    const float* W2 = (const float*)d_in[5];
    const float* b2 = (const float*)d_in[6];
    float* out = (float*)d_out;

    const int n = in_sizes[0];
    const int block = 256;
    const int grid = (n + block - 1) / block;
    pinn_taylor_kernel<<<grid, block, 0, stream>>>(x, W0, b0, W1, b1, W2, b2, out, n);
}

// Round 2
// 130.420 us; speedup vs baseline: 1.0706x; 1.0706x over previous
//
#include <hip/hip_runtime.h>
#include <hip/hip_bf16.h>
#include <math.h>

// PINN forward + Taylor-mode derivatives (orders 0..4), fully closed form.
// Outputs per point: [u, u_x, u_xx, w, w_x, w_xx, w_xxx, w_xxxx]  (row-major [N,8])
//
// Round 2 restructure: never materialize h0[5][8]/h1[5][8] arrays (round-1
// compiler spilled them at VGPR=44). Each layer-0 neuron's 5 Taylor coeffs are
// folded straight into the 40 layer-1 pre-activation accumulators; each
// layer-1 neuron's Faa-di-Bruno output folds straight into the 10 output
// accumulators. Peak live set ~55 floats.

__device__ __forceinline__ float fast_rcp(float x) {
#if __has_builtin(__builtin_amdgcn_rcpf)
    return __builtin_amdgcn_rcpf(x);   // v_rcp_f32, ~1 ulp
#else
    return 1.f / x;
#endif
}

__device__ __forceinline__ float fast_exp2(float x) {
#if __has_builtin(__builtin_amdgcn_exp2f)
    return __builtin_amdgcn_exp2f(x);  // v_exp_f32
#else
    return exp2f(x);
#endif
}

// tanh(z) = 1 - 2/(exp(2z)+1). exp2(+inf)->inf: rcp(inf)=0 -> t=1.
// exp2(-inf)->0: rcp(1)=1 -> t=-1. No clamp needed.
__device__ __forceinline__ float tanh_fast(float z) {
    const float e = fast_exp2(z * 2.88539008177792681472f);  // 2*log2(e)
    return fmaf(-2.f, fast_rcp(e + 1.f), 1.f);
}

__global__ __launch_bounds__(256, 2) void pinn_taylor_kernel(
    const float* __restrict__ x,
    const float* __restrict__ W0, const float* __restrict__ b0,
    const float* __restrict__ W1, const float* __restrict__ b1,
    const float* __restrict__ W2, const float* __restrict__ b2,
    float* __restrict__ out, int n)
{
    const int i = blockIdx.x * blockDim.x + threadIdx.x;
    if (i >= n) return;

    const float xv = x[i];  // L0 == 1.0

    // Layer-1 pre-activation Taylor accumulators g_k[ii], k = order 0..4
    float g0[8], g1[8], g2[8], g3[8], g4[8];
    #pragma unroll
    for (int ii = 0; ii < 8; ++ii) {
        g0[ii] = b1[ii];
        g1[ii] = 0.f; g2[ii] = 0.f; g3[ii] = 0.f; g4[ii] = 0.f;
    }

    // ---- layer 0 (affine in x => h0 coeffs are a^k * tanh^(k)(z)) fused into
    // ---- the layer-1 matvec over all 5 orders
    #pragma unroll
    for (int j = 0; j < 8; ++j) {
        const float a = W0[j];                 // W0 shape (8,1)
        const float z = fmaf(a, xv, b0[j]);
        const float t = tanh_fast(z);
        const float s  = fmaf(-t, t, 1.f);     // sech^2 = 1 - t^2
        const float T2 = -2.f * t * s;
        const float T3 = fmaf(4.f * t * t, s, -2.f * s * s);
        const float T4 = t * s * fmaf(-8.f, t * t, 16.f * s);
        const float a2 = a * a;
        const float d0 = t;
        const float d1 = a * s;
        const float d2 = a2 * T2;
        const float d3 = a2 * a * T3;
        const float d4 = a2 * a2 * T4;
        #pragma unroll
        for (int ii = 0; ii < 8; ++ii) {
            const float w = W1[ii * 8 + j];    // W1 shape (8,8) row-major
            g0[ii] = fmaf(w, d0, g0[ii]);
            g1[ii] = fmaf(w, d1, g1[ii]);
            g2[ii] = fmaf(w, d2, g2[ii]);
            g3[ii] = fmaf(w, d3, g3[ii]);
            g4[ii] = fmaf(w, d4, g4[ii]);
        }
    }

    // Output accumulators: o[k][order], k=0 -> u, k=1 -> w
    float ou0 = b2[0], ou1 = 0.f, ou2 = 0.f, ou3 = 0.f, ou4 = 0.f;
    float ow0 = b2[1], ow1 = 0.f, ow2 = 0.f, ow3 = 0.f, ow4 = 0.f;

    // ---- layer 1 tanh via Faa di Bruno, fused into layer-2 linear
    #pragma unroll
    for (int ii = 0; ii < 8; ++ii) {
        const float G1 = g1[ii], G2 = g2[ii], G3 = g3[ii], G4 = g4[ii];
        const float t = tanh_fast(g0[ii]);
        const float s  = fmaf(-t, t, 1.f);
        const float T2 = -2.f * t * s;
        const float T3 = fmaf(4.f * t * t, s, -2.f * s * s);
        const float T4 = t * s * fmaf(-8.f, t * t, 16.f * s);

        const float G1_2 = G1 * G1;
        const float d0 = t;
        const float d1 = s * G1;
        const float d2 = fmaf(T2, G1_2, s * G2);
        const float d3 = fmaf(T3, G1_2 * G1, fmaf(3.f * T2, G1 * G2, s * G3));
        const float d4 = fmaf(T4, G1_2 * G1_2,
                          fmaf(6.f * T3, G1_2 * G2,
                           fmaf(T2, fmaf(3.f, G2 * G2, 4.f * G1 * G3), s * G4)));

        const float wu = W2[ii];       // W2 shape (2,8) row-major: row 0 = u
        const float ww = W2[8 + ii];   //                           row 1 = w
        ou0 = fmaf(wu, d0, ou0); ou1 = fmaf(wu, d1, ou1); ou2 = fmaf(wu, d2, ou2);
        ou3 = fmaf(wu, d3, ou3); ou4 = fmaf(wu, d4, ou4);
        ow0 = fmaf(ww, d0, ow0); ow1 = fmaf(ww, d1, ow1); ow2 = fmaf(ww, d2, ow2);
        ow3 = fmaf(ww, d3, ow3); ow4 = fmaf(ww, d4, ow4);
    }

    // output row: u, u_x, u_xx, w, w_x, w_xx, w_xxx, w_xxxx
    float4* out4 = reinterpret_cast<float4*>(out);
    out4[2 * i + 0] = make_float4(ou0, ou1, ou2, ow0);
    out4[2 * i + 1] = make_float4(ow1, ow2, ow3, ow4);
}

extern "C" void kernel_launch(void* const* d_in, const int* in_sizes, int n_in,
                              void* d_out, int out_size, void* d_ws, size_t ws_size,
                              hipStream_t stream) {
    const float* x  = (const float*)d_in[0];
    const float* W0 = (const float*)d_in[1];
    const float* b0 = (const float*)d_in[2];
    const float* W1 = (const float*)d_in[3];
    const float* b1 = (const float*)d_in[4];
    const float* W2 = (const float*)d_in[5];
    const float* b2 = (const float*)d_in[6];
    float* out = (float*)d_out;

    const int n = in_sizes[0];
    const int block = 256;
    const int grid = (n + block - 1) / block;
    pinn_taylor_kernel<<<grid, block, 0, stream>>>(x, W0, b0, W1, b1, W2, b2, out, n);
}

// Round 3
// 109.619 us; speedup vs baseline: 1.2737x; 1.1898x over previous
//
#include <hip/hip_runtime.h>
#include <hip/hip_bf16.h>
#include <math.h>

// PINN forward + Taylor-mode derivatives (orders 0..4), closed form.
// Round 3: 2 points/thread, all Taylor math in <2 x float> (ext_vector_type)
// so the backend emits packed fp32 VOP3P (v_pk_fma_f32 / v_pk_mul_f32) —
// MI355X fp32 peak (157 TF) is only reachable via packed math.
// Outputs per point: [u, u_x, u_xx, w, w_x, w_xx, w_xxx, w_xxxx] (row-major [N,8])

typedef float v2f __attribute__((ext_vector_type(2)));

__device__ __forceinline__ v2f bc(float s) { v2f r; r.x = s; r.y = s; return r; }
__device__ __forceinline__ v2f vfma(v2f a, v2f b, v2f c) {
    return __builtin_elementwise_fma(a, b, c);
}

__device__ __forceinline__ float fast_rcp(float x) { return __builtin_amdgcn_rcpf(x); }
__device__ __forceinline__ float fast_exp2(float x) { return __builtin_amdgcn_exp2f(x); }

// tanh(z) = 1 - 2/(exp(2z)+1); exp2->inf: rcp(inf)=0 -> 1; exp2->0: rcp(1)=1 -> -1.
__device__ __forceinline__ v2f tanh2(v2f z) {
    const v2f a = bc(2.88539008177792681472f) * z;   // 2*log2(e)*z, packed
    v2f e;
    e.x = fast_exp2(a.x);
    e.y = fast_exp2(a.y);
    const v2f ep1 = e + bc(1.f);                     // packed add
    v2f r;
    r.x = fast_rcp(ep1.x);
    r.y = fast_rcp(ep1.y);
    return vfma(bc(-2.f), r, bc(1.f));               // packed fma
}

__global__ __launch_bounds__(256, 2) void pinn_taylor_kernel(
    const float* __restrict__ x,
    const float* __restrict__ W0, const float* __restrict__ b0,
    const float* __restrict__ W1, const float* __restrict__ b1,
    const float* __restrict__ W2, const float* __restrict__ b2,
    float* __restrict__ out, int n)
{
    const int i  = blockIdx.x * blockDim.x + threadIdx.x;
    const int p0 = 2 * i;
    if (p0 >= n) return;
    const bool full = (p0 + 1 < n);

    v2f xv;
    if (full) {
        const float2 xx = *reinterpret_cast<const float2*>(x + p0);
        xv.x = xx.x; xv.y = xx.y;
    } else {
        xv.x = x[p0]; xv.y = 0.f;
    }

    // Layer-1 pre-activation Taylor accumulators, orders 0..4, 8 neurons, 2 pts
    v2f g0[8], g1[8], g2[8], g3[8], g4[8];

    // ---- layer 0 (affine in x) fused into layer-1 matvec over all 5 orders
    #pragma unroll
    for (int j = 0; j < 8; ++j) {
        const float a  = W0[j];                  // W0 shape (8,1)
        const v2f   z  = vfma(bc(a), xv, bc(b0[j]));
        const v2f   t  = tanh2(z);
        const v2f   s  = vfma(-t, t, bc(1.f));   // sech^2
        const v2f   ts = t * s;
        const v2f   t2 = t * t;
        const v2f   s2 = s * s;
        const v2f   T2 = bc(-2.f) * ts;
        const v2f   T3 = vfma(bc(4.f) * t2, s, bc(-2.f) * s2);
        const v2f   T4 = ts * vfma(bc(-8.f), t2, bc(16.f) * s);
        const float a2 = a * a;
        const float a3 = a2 * a;
        const float a4 = a2 * a2;
        const v2f d0 = t;
        const v2f d1 = bc(a)  * s;
        const v2f d2 = bc(a2) * T2;
        const v2f d3 = bc(a3) * T3;
        const v2f d4 = bc(a4) * T4;
        #pragma unroll
        for (int ii = 0; ii < 8; ++ii) {
            const float w = W1[ii * 8 + j];      // W1 shape (8,8) row-major
            if (j == 0) {                        // peel: kills 40 zero/bias init movs
                g0[ii] = vfma(bc(w), d0, bc(b1[ii]));
                g1[ii] = bc(w) * d1;
                g2[ii] = bc(w) * d2;
                g3[ii] = bc(w) * d3;
                g4[ii] = bc(w) * d4;
            } else {
                g0[ii] = vfma(bc(w), d0, g0[ii]);
                g1[ii] = vfma(bc(w), d1, g1[ii]);
                g2[ii] = vfma(bc(w), d2, g2[ii]);
                g3[ii] = vfma(bc(w), d3, g3[ii]);
                g4[ii] = vfma(bc(w), d4, g4[ii]);
            }
        }
    }

    // Output heads: u needs orders 0..2 only, w needs 0..4
    v2f ou0 = bc(b2[0]), ou1 = bc(0.f), ou2 = bc(0.f);
    v2f ow0 = bc(b2[1]), ow1 = bc(0.f), ow2 = bc(0.f), ow3 = bc(0.f), ow4 = bc(0.f);

    // ---- layer 1 tanh via Faa di Bruno, fused into layer-2 linear
    #pragma unroll
    for (int ii = 0; ii < 8; ++ii) {
        const v2f G1 = g1[ii], G2 = g2[ii], G3 = g3[ii], G4 = g4[ii];
        const v2f t  = tanh2(g0[ii]);
        const v2f s  = vfma(-t, t, bc(1.f));
        const v2f ts = t * s;
        const v2f t2 = t * t;
        const v2f s2 = s * s;
        const v2f T2 = bc(-2.f) * ts;
        const v2f T3 = vfma(bc(4.f) * t2, s, bc(-2.f) * s2);
        const v2f T4 = ts * vfma(bc(-8.f), t2, bc(16.f) * s);

        const v2f G1_2 = G1 * G1;
        const v2f d0 = t;
        const v2f d1 = s * G1;
        const v2f d2 = vfma(T2, G1_2, s * G2);
        const v2f d3 = vfma(T3, G1_2 * G1, vfma(bc(3.f) * T2, G1 * G2, s * G3));
        const v2f d4 = vfma(T4, G1_2 * G1_2,
                        vfma(bc(6.f) * T3, G1_2 * G2,
                         vfma(T2, vfma(bc(3.f), G2 * G2, bc(4.f) * (G1 * G3)), s * G4)));

        const float wu = W2[ii];       // W2 (2,8) row-major: row 0 = u
        const float ww = W2[8 + ii];   //                     row 1 = w
        ou0 = vfma(bc(wu), d0, ou0); ou1 = vfma(bc(wu), d1, ou1); ou2 = vfma(bc(wu), d2, ou2);
        ow0 = vfma(bc(ww), d0, ow0); ow1 = vfma(bc(ww), d1, ow1); ow2 = vfma(bc(ww), d2, ow2);
        ow3 = vfma(bc(ww), d3, ow3); ow4 = vfma(bc(ww), d4, ow4);
    }

    // output rows: u, u_x, u_xx, w, w_x, w_xx, w_xxx, w_xxxx
    float4* out4 = reinterpret_cast<float4*>(out);
    out4[4 * i + 0] = make_float4(ou0.x, ou1.x, ou2.x, ow0.x);
    out4[4 * i + 1] = make_float4(ow1.x, ow2.x, ow3.x, ow4.x);
    if (full) {
        out4[4 * i + 2] = make_float4(ou0.y, ou1.y, ou2.y, ow0.y);
        out4[4 * i + 3] = make_float4(ow1.y, ow2.y, ow3.y, ow4.y);
    }
}

extern "C" void kernel_launch(void* const* d_in, const int* in_sizes, int n_in,
                              void* d_out, int out_size, void* d_ws, size_t ws_size,
                              hipStream_t stream) {
    const float* x  = (const float*)d_in[0];
    const float* W0 = (const float*)d_in[1];
    const float* b0 = (const float*)d_in[2];
    const float* W1 = (const float*)d_in[3];
    const float* b1 = (const float*)d_in[4];
    const float* W2 = (const float*)d_in[5];
    const float* b2 = (const float*)d_in[6];
    float* out = (float*)d_out;

    const int n = in_sizes[0];
    const int nthreads = (n + 1) / 2;
    const int block = 256;
    const int grid = (nthreads + block - 1) / block;
    pinn_taylor_kernel<<<grid, block, 0, stream>>>(x, W0, b0, W1, b1, W2, b2, out, n);
}